// Round 1
// baseline (317.084 us; speedup 1.0000x reference)
//
#include <hip/hip_runtime.h>
#include <stdint.h>

// Problem constants: B=2, H=16, S=2048, D=64; chunk_size irrelevant (telescopes).
#define BH_N 32
#define SEQ  2048
#define DH   64
#define SCALE 0.125f

typedef __attribute__((ext_vector_type(8))) short short8;   // 8 bf16 (4 VGPRs)
typedef __attribute__((ext_vector_type(4))) float f32x4;    // MFMA C/D

static __device__ __forceinline__ unsigned short f2bf(float f) {
  unsigned int u = __float_as_uint(f);
  u += 0x7fffu + ((u >> 16) & 1u);   // RNE
  return (unsigned short)(u >> 16);
}

// ---------------------------------------------------------------------------
// Prep: K -> bf16 row-major Kb[bh][s][d]; V -> bf16 transposed Vt[bh][d][s]
// ---------------------------------------------------------------------------
__global__ __launch_bounds__(256) void prep_kernel(
    const float* __restrict__ kin, const float* __restrict__ vin,
    unsigned short* __restrict__ kb, unsigned short* __restrict__ vt)
{
  const int sb = blockIdx.x;    // s-block 0..31 (64 rows each)
  const int bh = blockIdx.y;    // 0..31
  const int t  = threadIdx.x;   // 0..255
  __shared__ __align__(16) unsigned short tile[64][72];  // [d][c], padded

  const size_t base = ((size_t)bh * SEQ + (size_t)sb * 64) * DH;

  // K: elementwise fp32 -> bf16, same layout
  #pragma unroll
  for (int i = 0; i < 4; ++i) {
    int lin = i * 1024 + t * 4;
    float4 f = *reinterpret_cast<const float4*>(kin + base + lin);
    uint2 pk;
    pk.x = (unsigned)f2bf(f.x) | ((unsigned)f2bf(f.y) << 16);
    pk.y = (unsigned)f2bf(f.z) | ((unsigned)f2bf(f.w) << 16);
    *reinterpret_cast<uint2*>(kb + base + lin) = pk;
  }

  // V: read [c][d] coalesced, transpose through LDS, write Vt[bh][d][s]
  #pragma unroll
  for (int i = 0; i < 4; ++i) {
    int lin = i * 1024 + t * 4;
    int c = lin >> 6, f0 = lin & 63;
    float4 f = *reinterpret_cast<const float4*>(vin + base + lin);
    tile[f0 + 0][c] = f2bf(f.x);
    tile[f0 + 1][c] = f2bf(f.y);
    tile[f0 + 2][c] = f2bf(f.z);
    tile[f0 + 3][c] = f2bf(f.w);
  }
  __syncthreads();
  {
    int f = t >> 2, coff = (t & 3) * 16;
    unsigned short* vout = vt + ((size_t)bh * DH + f) * SEQ + (size_t)sb * 64 + coff;
    uint4 a = *reinterpret_cast<uint4*>(&tile[f][coff]);
    uint4 b = *reinterpret_cast<uint4*>(&tile[f][coff + 8]);
    *reinterpret_cast<uint4*>(vout)     = a;
    *reinterpret_cast<uint4*>(vout + 8) = b;
  }
}

// ---------------------------------------------------------------------------
// Causal attention with phi(s) = s + 0.5 s^2, s = (q*scale).k
// grid: (32 q-tiles of 64 rows, 32 bh). 4 waves/block, 16 q-rows per wave.
// ---------------------------------------------------------------------------
__global__ __launch_bounds__(256) void attn_kernel(
    const float* __restrict__ q,
    const unsigned short* __restrict__ kb,
    const unsigned short* __restrict__ vt,
    float* __restrict__ out)
{
  const int qtile = blockIdx.x;       // 0..31
  const int bh    = blockIdx.y;       // 0..31
  const int w     = threadIdx.x >> 6; // wave 0..3
  const int lane  = threadIdx.x & 63;
  const int low   = lane & 15;
  const int quad  = lane >> 4;

  // Per-wave P staging in exact A-fragment order: [wave][kstep][lane][j]
  __shared__ __align__(16) unsigned short pbuf[4][2][64][8];

  const int qrow0 = qtile * 64 + w * 16;

  // Q A-fragments (scaled, bf16), kept in registers for the whole kernel.
  short8 aq[2];
  {
    const float* qp = q + ((size_t)bh * SEQ + qrow0 + low) * DH + quad * 8;
    #pragma unroll
    for (int ks = 0; ks < 2; ++ks) {
      float4 f0 = *reinterpret_cast<const float4*>(qp + ks * 32);
      float4 f1 = *reinterpret_cast<const float4*>(qp + ks * 32 + 4);
      short8 a;
      a[0] = (short)f2bf(f0.x * SCALE); a[1] = (short)f2bf(f0.y * SCALE);
      a[2] = (short)f2bf(f0.z * SCALE); a[3] = (short)f2bf(f0.w * SCALE);
      a[4] = (short)f2bf(f1.x * SCALE); a[5] = (short)f2bf(f1.y * SCALE);
      a[6] = (short)f2bf(f1.z * SCALE); a[7] = (short)f2bf(f1.w * SCALE);
      aq[ks] = a;
    }
  }

  f32x4 oacc[4];
  #pragma unroll
  for (int i = 0; i < 4; ++i) oacc[i] = (f32x4){0.f, 0.f, 0.f, 0.f};

  const unsigned short* kb_h = kb + (size_t)bh * SEQ * DH;
  const unsigned short* vt_h = vt + (size_t)bh * DH * SEQ;

  for (int t = 0; t <= qtile; ++t) {
    const int kbase = t * 64;

    // ---- S = Q K^T (16 x 64 per wave) ----
    f32x4 sacc[4];
    #pragma unroll
    for (int i = 0; i < 4; ++i) sacc[i] = (f32x4){0.f, 0.f, 0.f, 0.f};

    #pragma unroll
    for (int ks = 0; ks < 2; ++ks) {
      #pragma unroll
      for (int nt = 0; nt < 4; ++nt) {
        short8 bk = *reinterpret_cast<const short8*>(
            kb_h + (size_t)(kbase + nt * 16 + low) * DH + ks * 32 + quad * 8);
        sacc[nt] = __builtin_amdgcn_mfma_f32_16x16x32_bf16(aq[ks], bk, sacc[nt], 0, 0, 0);
      }
    }

    // ---- phi + causal mask, pack bf16, scatter into A-frag-ordered LDS ----
    // D layout: element [row = quad*4+reg][col = nt*16+low]
    #pragma unroll
    for (int nt = 0; nt < 4; ++nt) {
      #pragma unroll
      for (int r = 0; r < 4; ++r) {
        float s = sacc[nt][r];
        float p = __builtin_fmaf(0.5f * s, s, s);       // s + 0.5 s^2
        int kcol = kbase + nt * 16 + low;
        int qrow = qrow0 + quad * 4 + r;
        if (kcol > qrow) p = 0.f;                        // only bites on diagonal tile
        // dest: P[m = quad*4+r][c = nt*16+low] -> pbuf[w][c/32][((c%32)/8)*16 + m][c%8]
        pbuf[w][nt >> 1][(((nt & 1) << 1) + (low >> 3)) * 16 + quad * 4 + r][low & 7] =
            f2bf(p);
      }
    }
    asm volatile("s_waitcnt lgkmcnt(0)" ::: "memory");   // wave-local: no barrier needed

    short8 ap0 = *reinterpret_cast<const short8*>(&pbuf[w][0][lane][0]);
    short8 ap1 = *reinterpret_cast<const short8*>(&pbuf[w][1][lane][0]);

    // ---- O += P V ----
    #pragma unroll
    for (int ks = 0; ks < 2; ++ks) {
      short8 apk = ks ? ap1 : ap0;
      #pragma unroll
      for (int ft = 0; ft < 4; ++ft) {
        short8 bv = *reinterpret_cast<const short8*>(
            vt_h + (size_t)(ft * 16 + low) * SEQ + kbase + ks * 32 + quad * 8);
        oacc[ft] = __builtin_amdgcn_mfma_f32_16x16x32_bf16(apk, bv, oacc[ft], 0, 0, 0);
      }
    }
  }

  // ---- epilogue: C/D layout -> global fp32 ----
  #pragma unroll
  for (int ft = 0; ft < 4; ++ft) {
    #pragma unroll
    for (int r = 0; r < 4; ++r) {
      out[((size_t)bh * SEQ + qrow0 + quad * 4 + r) * DH + ft * 16 + low] = oacc[ft][r];
    }
  }
}

extern "C" void kernel_launch(void* const* d_in, const int* in_sizes, int n_in,
                              void* d_out, int out_size, void* d_ws, size_t ws_size,
                              hipStream_t stream)
{
  const float* q = (const float*)d_in[0];
  const float* k = (const float*)d_in[1];
  const float* v = (const float*)d_in[2];
  float* out = (float*)d_out;

  unsigned short* kb = (unsigned short*)d_ws;                  //  8.4 MB bf16
  unsigned short* vt = kb + (size_t)BH_N * SEQ * DH;           //  8.4 MB bf16

  dim3 grid(32, BH_N);
  prep_kernel<<<grid, 256, 0, stream>>>(k, v, kb, vt);
  attn_kernel<<<grid, 256, 0, stream>>>(q, kb, vt, out);
}

// Round 2
// 155.562 us; speedup vs baseline: 2.0383x; 2.0383x over previous
//
#include <hip/hip_runtime.h>
#include <stdint.h>

// B=2,H=16 -> BH=32; S=2048, D=64. chunk_size telescopes out:
// out = causal attention with phi(s)=s+0.5*s^2, s=(q*D^-0.5).k
#define SEQ  2048
#define DH   64
#define BH_N 32
#define SCALE 0.125f

typedef __attribute__((ext_vector_type(8))) short short8;   // 8 bf16
typedef __attribute__((ext_vector_type(4))) float f32x4;    // MFMA C/D

static __device__ __forceinline__ unsigned short f2bf(float f) {
  unsigned int u = __float_as_uint(f);
  u += 0x7fffu + ((u >> 16) & 1u);   // RNE
  return (unsigned short)(u >> 16);
}

typedef __attribute__((address_space(1))) const unsigned char* gp1;
typedef __attribute__((address_space(3))) unsigned char* lp3;
static __device__ __forceinline__ void stage16(const void* g, void* l) {
  // wave-uniform LDS base + lane*16, 16B per lane
  __builtin_amdgcn_global_load_lds((gp1)g, (lp3)l, 16, 0, 0);
}

// ---------------------------------------------------------------------------
// Prep: K fp32 -> bf16 row-major Kb[bh][s][d];  V fp32 -> bf16 Vt[bh][d][s].
// No LDS: V transpose via coalesced lane-major column reads (lane = d).
// ---------------------------------------------------------------------------
__global__ __launch_bounds__(256) void prep_kernel(
    const float* __restrict__ kin, const float* __restrict__ vin,
    unsigned short* __restrict__ kb, unsigned short* __restrict__ vt)
{
  const int sb = blockIdx.x;    // 0..31 (64 s-rows each)
  const int bh = blockIdx.y;    // 0..31
  const int t  = threadIdx.x;   // 0..255
  const size_t base = ((size_t)bh * SEQ + (size_t)sb * 64) * DH;

  // K: elementwise fp32 -> bf16
  #pragma unroll
  for (int i = 0; i < 4; ++i) {
    int lin = i * 1024 + t * 4;
    float4 f = *reinterpret_cast<const float4*>(kin + base + lin);
    uint2 pk;
    pk.x = (unsigned)f2bf(f.x) | ((unsigned)f2bf(f.y) << 16);
    pk.y = (unsigned)f2bf(f.z) | ((unsigned)f2bf(f.w) << 16);
    *reinterpret_cast<uint2*>(kb + base + lin) = pk;
  }

  // V transpose: thread (d = t&63, sg = t>>6) reads 16 s at stride D (coalesced
  // across lanes: 64 lanes = one 256B row segment per j), writes 32B contiguous.
  {
    const int d = t & 63, sg = t >> 6;
    const float* vp = vin + base + (size_t)sg * 16 * DH + d;
    unsigned short tmp[16];
    #pragma unroll
    for (int j = 0; j < 16; ++j) tmp[j] = f2bf(vp[(size_t)j * DH]);
    unsigned short* vo = vt + ((size_t)bh * DH + d) * SEQ + sb * 64 + sg * 16;
    *reinterpret_cast<uint4*>(vo)     = *reinterpret_cast<uint4*>(tmp);
    *reinterpret_cast<uint4*>(vo + 8) = *reinterpret_cast<uint4*>(tmp + 8);
  }
}

// ---------------------------------------------------------------------------
// attn: grid (16, 32). Block = pair of q-tiles (qa, 31-qa) -> 66 active
// wave-iters per block (perfect balance). 4 waves, wave w: tile = (w<2)?qa:31-qa,
// rows (w&1)*32 .. +32 (two 16-row MFMA row-halves).
// K/V tiles double-buffered in LDS via global_load_lds, prefetch kept in
// flight across raw s_barrier (manual vmcnt, no __syncthreads drain).
// LDS tile layout (per 64-key tile): chunk c = ks*4+quad (1KB each):
//   K: kls[c*512 + key*8 + j]  = K[key][ks*32+quad*8+j]
//   V: vls[c*512 + d*8 + j]    = Vt[d][ks*32+quad*8+j]
// -> fragment reads are contiguous short8 (2-way banks, free).
// ---------------------------------------------------------------------------
__global__ __launch_bounds__(256) void attn_kernel(
    const float* __restrict__ q,
    const unsigned short* __restrict__ kb,
    const unsigned short* __restrict__ vt,
    float* __restrict__ out)
{
  const int qa   = blockIdx.x;        // 0..15
  const int bh   = blockIdx.y;        // 0..31
  const int w    = threadIdx.x >> 6;  // 0..3
  const int lane = threadIdx.x & 63;
  const int low  = lane & 15;
  const int quad = lane >> 4;

  __shared__ __align__(16) unsigned short kls[2][4096];
  __shared__ __align__(16) unsigned short vls[2][4096];
  __shared__ __align__(16) unsigned short pbuf[4][2][2][64][8];

  const int mytile = (w < 2) ? qa : (31 - qa);
  const int tmax   = 31 - qa;                     // max tile needed in block
  const int r0     = mytile * 64 + (w & 1) * 32;  // wave's first q-row

  const unsigned short* kb_h = kb + (size_t)bh * SEQ * DH;
  const unsigned short* vt_h = vt + (size_t)bh * DH * SEQ;

  // Q A-fragments (scaled bf16), registers for whole kernel. [h][ks]
  short8 aq[2][2];
  #pragma unroll
  for (int h = 0; h < 2; ++h) {
    const float* qp = q + ((size_t)bh * SEQ + r0 + h * 16 + low) * DH + quad * 8;
    #pragma unroll
    for (int ks = 0; ks < 2; ++ks) {
      float4 f0 = *reinterpret_cast<const float4*>(qp + ks * 32);
      float4 f1 = *reinterpret_cast<const float4*>(qp + ks * 32 + 4);
      short8 a;
      a[0] = (short)f2bf(f0.x * SCALE); a[1] = (short)f2bf(f0.y * SCALE);
      a[2] = (short)f2bf(f0.z * SCALE); a[3] = (short)f2bf(f0.w * SCALE);
      a[4] = (short)f2bf(f1.x * SCALE); a[5] = (short)f2bf(f1.y * SCALE);
      a[6] = (short)f2bf(f1.z * SCALE); a[7] = (short)f2bf(f1.w * SCALE);
      aq[h][ks] = a;
    }
  }

  f32x4 oacc[2][4];
  #pragma unroll
  for (int h = 0; h < 2; ++h)
    #pragma unroll
    for (int i = 0; i < 4; ++i) oacc[h][i] = (f32x4){0.f, 0.f, 0.f, 0.f};

  // staging: wave w stages K chunks {w, w+4}, V chunks {w, w+4} (4 loads)
  const int offA = (w & 3) * 8;        // chunk w  (ks=0)
  const int offB = 32 + (w & 3) * 8;   // chunk w+4 (ks=1)

  #define STAGE_TILE(TT, B)                                                    \
    do {                                                                       \
      const int kbase_ = (TT) * 64;                                            \
      stage16(kb_h + (size_t)(kbase_ + lane) * 64 + offA, &kls[B][w * 512]);   \
      stage16(kb_h + (size_t)(kbase_ + lane) * 64 + offB, &kls[B][(w + 4) * 512]); \
      stage16(vt_h + (size_t)lane * 2048 + kbase_ + offA, &vls[B][w * 512]);   \
      stage16(vt_h + (size_t)lane * 2048 + kbase_ + offB, &vls[B][(w + 4) * 512]); \
    } while (0)

  STAGE_TILE(0, 0);

  for (int t = 0; t <= tmax; ++t) {
    const int b = t & 1;
    // barrier 1: all waves done reading buf[b^1] (previous iteration)
    __builtin_amdgcn_s_barrier();
    if (t < tmax) {
      STAGE_TILE(t + 1, b ^ 1);                       // prefetch stays in flight
      asm volatile("s_waitcnt vmcnt(4)" ::: "memory"); // own tile-t loads landed
    } else {
      asm volatile("s_waitcnt vmcnt(0)" ::: "memory");
    }
    // barrier 2: everyone's tile-t chunks landed in LDS
    __builtin_amdgcn_s_barrier();
    asm volatile("" ::: "memory");   // pin LDS reads after barrier 2

    if (t > mytile) continue;        // inactive wave: staging + barriers only

    // ---- S = Q K^T : two 16-row halves share each B fragment ----
    f32x4 sacc[2][4];
    #pragma unroll
    for (int h = 0; h < 2; ++h)
      #pragma unroll
      for (int i = 0; i < 4; ++i) sacc[h][i] = (f32x4){0.f, 0.f, 0.f, 0.f};

    #pragma unroll
    for (int ks = 0; ks < 2; ++ks) {
      #pragma unroll
      for (int nt = 0; nt < 4; ++nt) {
        short8 bk = *reinterpret_cast<const short8*>(
            &kls[b][(ks * 4 + quad) * 512 + (nt * 16 + low) * 8]);
        sacc[0][nt] = __builtin_amdgcn_mfma_f32_16x16x32_bf16(aq[0][ks], bk, sacc[0][nt], 0, 0, 0);
        sacc[1][nt] = __builtin_amdgcn_mfma_f32_16x16x32_bf16(aq[1][ks], bk, sacc[1][nt], 0, 0, 0);
      }
    }

    // ---- phi(s)=s+0.5 s^2, causal mask only on diagonal tile, pack to LDS ----
    const bool diag = (t == mytile);
    #pragma unroll
    for (int h = 0; h < 2; ++h) {
      #pragma unroll
      for (int nt = 0; nt < 4; ++nt) {
        #pragma unroll
        for (int r = 0; r < 4; ++r) {
          float s = sacc[h][nt][r];
          float p = __builtin_fmaf(0.5f * s, s, s);
          if (diag) {
            int kcol = nt * 16 + low;                       // within tile
            int qrow = (w & 1) * 32 + h * 16 + quad * 4 + r;
            if (kcol > qrow) p = 0.f;
          }
          pbuf[w][h][nt >> 1][(((nt & 1) << 1) + (low >> 3)) * 16 + quad * 4 + r]
              [low & 7] = f2bf(p);
        }
      }
    }

    // ---- O += P V (wave-local LDS roundtrip; compiler orders via aliasing) ----
    #pragma unroll
    for (int ks = 0; ks < 2; ++ks) {
      short8 ap0 = *reinterpret_cast<const short8*>(&pbuf[w][0][ks][lane][0]);
      short8 ap1 = *reinterpret_cast<const short8*>(&pbuf[w][1][ks][lane][0]);
      #pragma unroll
      for (int ft = 0; ft < 4; ++ft) {
        short8 bv = *reinterpret_cast<const short8*>(
            &vls[b][(ks * 4 + quad) * 512 + (ft * 16 + low) * 8]);
        oacc[0][ft] = __builtin_amdgcn_mfma_f32_16x16x32_bf16(ap0, bv, oacc[0][ft], 0, 0, 0);
        oacc[1][ft] = __builtin_amdgcn_mfma_f32_16x16x32_bf16(ap1, bv, oacc[1][ft], 0, 0, 0);
      }
    }
  }

  // ---- epilogue ----
  #pragma unroll
  for (int h = 0; h < 2; ++h)
    #pragma unroll
    for (int ft = 0; ft < 4; ++ft)
      #pragma unroll
      for (int r = 0; r < 4; ++r)
        out[((size_t)bh * SEQ + r0 + h * 16 + quad * 4 + r) * DH + ft * 16 + low] =
            oacc[h][ft][r];
}

extern "C" void kernel_launch(void* const* d_in, const int* in_sizes, int n_in,
                              void* d_out, int out_size, void* d_ws, size_t ws_size,
                              hipStream_t stream)
{
  const float* q = (const float*)d_in[0];
  const float* k = (const float*)d_in[1];
  const float* v = (const float*)d_in[2];
  float* out = (float*)d_out;

  unsigned short* kb = (unsigned short*)d_ws;              // 8.4 MB bf16
  unsigned short* vt = kb + (size_t)BH_N * SEQ * DH;       // 8.4 MB bf16

  prep_kernel<<<dim3(32, BH_N), 256, 0, stream>>>(k, v, kb, vt);
  attn_kernel<<<dim3(16, BH_N), 256, 0, stream>>>(q, kb, vt, out);
}

// Round 3
// 144.774 us; speedup vs baseline: 2.1902x; 1.0745x over previous
//
#include <hip/hip_runtime.h>
#include <stdint.h>

// B=2,H=16 -> BH=32; S=2048, D=64. chunk_size telescopes out:
// out = causal attention with phi(s)=s+0.5*s^2, s=(q*D^-0.5).k
#define SEQ  2048
#define DH   64
#define BH_N 32
#define SCALE 0.125f

typedef __attribute__((ext_vector_type(8))) short short8;   // 8 bf16
typedef __attribute__((ext_vector_type(4))) short short4b;  // 4 bf16
typedef __attribute__((ext_vector_type(4))) float f32x4;    // MFMA C/D

static __device__ __forceinline__ unsigned short f2bf(float f) {
  unsigned int u = __float_as_uint(f);
  u += 0x7fffu + ((u >> 16) & 1u);   // RNE
  return (unsigned short)(u >> 16);
}

typedef __attribute__((address_space(1))) const unsigned char* gp1;
typedef __attribute__((address_space(3))) unsigned char* lp3;
static __device__ __forceinline__ void stage16(const void* g, void* l) {
  __builtin_amdgcn_global_load_lds((gp1)g, (lp3)l, 16, 0, 0);
}

// ---------------------------------------------------------------------------
// Prep: K fp32 -> bf16 row-major Kb[bh][s][d].
//       V fp32 -> bf16 Vt2: PV A-fragment-order units per 64-key tile:
//       unit u = kgp*256 + ft*64 + quad*16 + low  (512 units x 16B per tile)
//       shorts[j]: kg = kgp*2 + (j>>2); key = kg*16 + quad*4 + (j&3);
//                  f = ft*16 + low;  value = V[tile*64+key][f]
// ---------------------------------------------------------------------------
__global__ __launch_bounds__(256) void prep_kernel(
    const float* __restrict__ kin, const float* __restrict__ vin,
    unsigned short* __restrict__ kb, unsigned short* __restrict__ vt2)
{
  const int sb = blockIdx.x;    // 0..31 (64 s each)
  const int bh = blockIdx.y;    // 0..31
  const int t  = threadIdx.x;   // 0..255
  const size_t base = ((size_t)bh * SEQ + (size_t)sb * 64) * DH;

  // K: elementwise fp32 -> bf16
  #pragma unroll
  for (int i = 0; i < 4; ++i) {
    int lin = i * 1024 + t * 4;
    float4 f = *reinterpret_cast<const float4*>(kin + base + lin);
    uint2 pk;
    pk.x = (unsigned)f2bf(f.x) | ((unsigned)f2bf(f.y) << 16);
    pk.y = (unsigned)f2bf(f.z) | ((unsigned)f2bf(f.w) << 16);
    *reinterpret_cast<uint2*>(kb + base + lin) = pk;
  }

  // V -> Vt2 fragment units (2 units per thread)
  #pragma unroll
  for (int uu = 0; uu < 2; ++uu) {
    const int u   = uu * 256 + t;
    const int kgp = u >> 8, ft = (u >> 6) & 3, qd = (u >> 4) & 3, lo = u & 15;
    unsigned short sh[8];
    #pragma unroll
    for (int j = 0; j < 8; ++j) {
      int kg  = kgp * 2 + (j >> 2);
      int key = kg * 16 + qd * 4 + (j & 3);
      sh[j] = f2bf(vin[base + (size_t)key * DH + ft * 16 + lo]);
    }
    uint4 pk;
    pk.x = (unsigned)sh[0] | ((unsigned)sh[1] << 16);
    pk.y = (unsigned)sh[2] | ((unsigned)sh[3] << 16);
    pk.z = (unsigned)sh[4] | ((unsigned)sh[5] << 16);
    pk.w = (unsigned)sh[6] | ((unsigned)sh[7] << 16);
    *reinterpret_cast<uint4*>(vt2 + (((size_t)bh * 32 + sb) * 512 + u) * 8) = pk;
  }
}

// ---------------------------------------------------------------------------
// attn: grid (16, 32), 512 threads (8 waves).
// Wave w: parity p=w>>2 (even/odd kv-tiles), q-tile = (w>>1)&1 ? 31-qa : qa,
// row-half rh=w&1 (32 q-rows per wave). Split-K partials merged via LDS.
// Per barrier-iteration: stage kv-tile pair (2i, 2i+1) via global_load_lds,
// double-buffered, prefetch in flight across raw s_barrier (vmcnt(4)).
// S^T = K.Q^T (16x16x32, A=K, B=Q)  ->  phi in-register -> P^T B-frags
// O^T += V^T.P^T (16x16x16)  -> dwordx4 epilogue stores.
// ---------------------------------------------------------------------------
__global__ __launch_bounds__(512, 4) void attn_kernel(
    const float* __restrict__ q,
    const unsigned short* __restrict__ kb,
    const unsigned short* __restrict__ vt2,
    float* __restrict__ out)
{
  const int qa   = blockIdx.x;        // 0..15
  const int bh   = blockIdx.y;        // 0..31
  const int tid  = threadIdx.x;
  const int w    = tid >> 6;          // 0..7
  const int lane = tid & 63;
  const int low  = lane & 15;
  const int quad = lane >> 4;
  const int p    = w >> 2;            // kv-tile parity
  const int qsel = (w >> 1) & 1;
  const int rh   = w & 1;

  const int mytile = qsel ? (31 - qa) : qa;
  const int tmax   = 31 - qa;
  const int imax   = tmax >> 1;
  const int r0     = mytile * 64 + rh * 32;

  // [buf][pair-member p][chunk c=ks*4+quad][key*8+j]
  __shared__ __align__(16) unsigned short kls[2][2][8][512];
  // [buf][pair-member p][unit u][j]
  __shared__ __align__(16) unsigned short vls[2][2][512][8];

  const unsigned short* kb_h = kb  + (size_t)bh * SEQ * DH;
  const unsigned short* v2_h = vt2 + (size_t)bh * 32 * 512 * 8;

  // Q B-frags (scaled bf16): lane low = q-row, k = ks*32+quad*8+j
  short8 aq[2][2];
  #pragma unroll
  for (int h = 0; h < 2; ++h) {
    const float* qp = q + ((size_t)bh * SEQ + r0 + h * 16 + low) * DH + quad * 8;
    #pragma unroll
    for (int ks = 0; ks < 2; ++ks) {
      float4 f0 = *reinterpret_cast<const float4*>(qp + ks * 32);
      float4 f1 = *reinterpret_cast<const float4*>(qp + ks * 32 + 4);
      short8 a;
      a[0] = (short)f2bf(f0.x * SCALE); a[1] = (short)f2bf(f0.y * SCALE);
      a[2] = (short)f2bf(f0.z * SCALE); a[3] = (short)f2bf(f0.w * SCALE);
      a[4] = (short)f2bf(f1.x * SCALE); a[5] = (short)f2bf(f1.y * SCALE);
      a[6] = (short)f2bf(f1.z * SCALE); a[7] = (short)f2bf(f1.w * SCALE);
      aq[h][ks] = a;
    }
  }

  f32x4 oacc[2][4];   // O^T: lane holds O[q=r0+h*16+low][f=ft*16+quad*4+r]
  #pragma unroll
  for (int h = 0; h < 2; ++h)
    #pragma unroll
    for (int i = 0; i < 4; ++i) oacc[h][i] = (f32x4){0.f, 0.f, 0.f, 0.f};

  const int cc = w & 3, pp = w >> 2;   // staging role: tile-member pp, chunk cc

  #define STAGE(IP, B)                                                           \
    do {                                                                         \
      const int tile_ = (IP) * 2 + pp;                                           \
      stage16(kb_h + (size_t)(tile_ * 64 + lane) * 64 + cc * 8,                  \
              &kls[B][pp][cc][0]);                                               \
      stage16(kb_h + (size_t)(tile_ * 64 + lane) * 64 + 32 + cc * 8,             \
              &kls[B][pp][cc + 4][0]);                                           \
      stage16(v2_h + (size_t)(tile_ * 512 + cc * 64 + lane) * 8,                 \
              &vls[B][pp][cc * 64][0]);                                          \
      stage16(v2_h + (size_t)(tile_ * 512 + (cc + 4) * 64 + lane) * 8,           \
              &vls[B][pp][(cc + 4) * 64][0]);                                    \
    } while (0)

  STAGE(0, 0);

  for (int i = 0; i <= imax; ++i) {
    const int b = i & 1;
    __builtin_amdgcn_s_barrier();                       // buf b^1 free to overwrite
    if (i < imax) {
      STAGE(i + 1, b ^ 1);                              // prefetch stays in flight
      asm volatile("s_waitcnt vmcnt(4)" ::: "memory");  // own pair-i loads landed
    } else {
      asm volatile("s_waitcnt vmcnt(0)" ::: "memory");
    }
    __builtin_amdgcn_s_barrier();                       // everyone's pair-i landed
    asm volatile("" ::: "memory");

    const int tt = 2 * i + p;
    if (tt > mytile) continue;                          // wave-uniform
    const bool diag = (tt == mytile);

    const unsigned short* kT = &kls[b][p][0][0];
    const unsigned short* vT = &vls[b][p][0][0];

    #pragma unroll
    for (int ntp = 0; ntp < 2; ++ntp) {
      short8 vf[4];
      #pragma unroll
      for (int ft = 0; ft < 4; ++ft)
        vf[ft] = *reinterpret_cast<const short8*>(
            vT + (ntp * 256 + ft * 64 + quad * 16 + low) * 8);

      #pragma unroll
      for (int sub = 0; sub < 2; ++sub) {
        const int nt = ntp * 2 + sub;

        // S^T tile (16 keys x 16 q) for both q-halves
        f32x4 s0 = (f32x4){0.f, 0.f, 0.f, 0.f};
        f32x4 s1 = (f32x4){0.f, 0.f, 0.f, 0.f};
        #pragma unroll
        for (int ks = 0; ks < 2; ++ks) {
          short8 kf = *reinterpret_cast<const short8*>(
              kT + (ks * 4 + quad) * 512 + (nt * 16 + low) * 8);
          s0 = __builtin_amdgcn_mfma_f32_16x16x32_bf16(kf, aq[0][ks], s0, 0, 0, 0);
          s1 = __builtin_amdgcn_mfma_f32_16x16x32_bf16(kf, aq[1][ks], s1, 0, 0, 0);
        }

        #pragma unroll
        for (int h = 0; h < 2; ++h) {
          f32x4 s = h ? s1 : s0;
          short4b pf;   // P^T B-frag: k = quad*4+r, n = q = low
          #pragma unroll
          for (int r = 0; r < 4; ++r) {
            float x = s[r];
            float v = __builtin_fmaf(0.5f * x, x, x);   // s + 0.5 s^2
            if (diag && (nt * 16 + quad * 4 + r) > (rh * 32 + h * 16 + low)) v = 0.f;
            pf[r] = (short)f2bf(v);
          }
          #pragma unroll
          for (int ft = 0; ft < 4; ++ft) {
            short4b va = sub
                ? __builtin_shufflevector(vf[ft], vf[ft], 4, 5, 6, 7)
                : __builtin_shufflevector(vf[ft], vf[ft], 0, 1, 2, 3);
            oacc[h][ft] =
                __builtin_amdgcn_mfma_f32_16x16x16bf16_1k(va, pf, oacc[h][ft], 0, 0, 0);
          }
        }
      }
    }
  }

  // ---- split-K merge via LDS (reuse kls region: 4 x 8KB) + epilogue ----
  __syncthreads();
  float* mb = reinterpret_cast<float*>(&kls[0][0][0][0]);
  float* mw = mb + (size_t)(w & 3) * 2048;
  if (p == 1) {
    #pragma unroll
    for (int h = 0; h < 2; ++h)
      #pragma unroll
      for (int ft = 0; ft < 4; ++ft)
        *reinterpret_cast<f32x4*>(&mw[(h * 4 + ft) * 256 + low * 16 + quad * 4]) =
            oacc[h][ft];
  }
  __syncthreads();
  if (p == 0) {
    #pragma unroll
    for (int h = 0; h < 2; ++h) {
      #pragma unroll
      for (int ft = 0; ft < 4; ++ft) {
        f32x4 o = oacc[h][ft];
        f32x4 m = *reinterpret_cast<const f32x4*>(
            &mw[(h * 4 + ft) * 256 + low * 16 + quad * 4]);
        o += m;
        *reinterpret_cast<f32x4*>(
            &out[((size_t)bh * SEQ + r0 + h * 16 + low) * DH + ft * 16 + quad * 4]) = o;
      }
    }
  }
}

extern "C" void kernel_launch(void* const* d_in, const int* in_sizes, int n_in,
                              void* d_out, int out_size, void* d_ws, size_t ws_size,
                              hipStream_t stream)
{
  const float* q = (const float*)d_in[0];
  const float* k = (const float*)d_in[1];
  const float* v = (const float*)d_in[2];
  float* out = (float*)d_out;

  unsigned short* kb  = (unsigned short*)d_ws;             // 8.4 MB bf16
  unsigned short* vt2 = kb + (size_t)BH_N * SEQ * DH;      // 8.4 MB bf16

  prep_kernel<<<dim3(32, BH_N), 256, 0, stream>>>(k, v, kb, vt2);
  attn_kernel<<<dim3(16, BH_N), 512, 0, stream>>>(q, kb, vt2, out);
}

// Round 4
// 128.181 us; speedup vs baseline: 2.4737x; 1.1294x over previous
//
#include <hip/hip_runtime.h>
#include <stdint.h>

// B=2,H=16 -> BH=32; S=2048, D=64. chunk_size telescopes out:
// out = causal attention with phi(s)=s+0.5*s^2, s=(q*D^-0.5).k
#define SEQ  2048
#define DH   64
#define BH_N 32
#define SCALE 0.125f

typedef __attribute__((ext_vector_type(8))) short short8;   // 8 bf16
typedef __attribute__((ext_vector_type(4))) short short4b;  // 4 bf16
typedef __attribute__((ext_vector_type(4))) float f32x4;    // MFMA C/D

static __device__ __forceinline__ unsigned short f2bf(float f) {
  unsigned int u = __float_as_uint(f);
  u += 0x7fffu + ((u >> 16) & 1u);   // RNE
  return (unsigned short)(u >> 16);
}
// pack RNE(a)|RNE(b)<<16 with one v_perm for the pack
static __device__ __forceinline__ unsigned packbf(float a, float b) {
  unsigned ua = __float_as_uint(a); ua += 0x7fffu + ((ua >> 16) & 1u);
  unsigned ub = __float_as_uint(b); ub += 0x7fffu + ((ub >> 16) & 1u);
  return __builtin_amdgcn_perm(ub, ua, 0x07060302);  // [ub_hi16 : ua_hi16]
}

typedef __attribute__((address_space(1))) const unsigned char* gp1;
typedef __attribute__((address_space(3))) unsigned char* lp3;
static __device__ __forceinline__ void stage16(const void* g, void* l) {
  __builtin_amdgcn_global_load_lds((gp1)g, (lp3)l, 16, 0, 0);
}

// ---------------------------------------------------------------------------
// Prep: per (bh, 64-key tile) produce stage-ready 16B units (512/tile):
//  kb2 unit u = c*64+key (c=ks*4+quad): shorts j = K[key][ks*32+quad*8+j] (bf16)
//  vt2 unit u = kgp*256+ft*64+quad*16+low: shorts j: kg=kgp*2+(j>>2),
//      key=kg*16+quad*4+(j&3), value = V[key][ft*16+low] (bf16)
// Coalesced float4 reads -> LDS repack -> coalesced uint4 writes.
// ---------------------------------------------------------------------------
__global__ __launch_bounds__(256) void prep_kernel(
    const float* __restrict__ kin, const float* __restrict__ vin,
    unsigned short* __restrict__ kb2, unsigned short* __restrict__ vt2)
{
  const int sb = blockIdx.x;    // 0..31 (64 keys each)
  const int bh = blockIdx.y;    // 0..31
  const int t  = threadIdx.x;   // 0..255
  __shared__ __align__(16) unsigned short lds[4096];
  const size_t base  = ((size_t)bh * SEQ + (size_t)sb * 64) * DH;
  const size_t obase = ((size_t)bh * 32 + sb) * 4096;   // shorts per tile

  // ---- K ----
  #pragma unroll
  for (int i = 0; i < 4; ++i) {
    int idx = i * 256 + t, key = idx >> 4, F = (idx & 15) * 4;
    float4 f = *reinterpret_cast<const float4*>(kin + base + key * DH + F);
    int c = (F >> 5) * 4 + ((F >> 3) & 3), jh = (F >> 2) & 1;
    uint2 pk; pk.x = packbf(f.x, f.y); pk.y = packbf(f.z, f.w);
    *reinterpret_cast<uint2*>(lds + (c * 64 + key) * 8 + jh * 4) = pk;
  }
  __syncthreads();
  #pragma unroll
  for (int uu = 0; uu < 2; ++uu) {
    int u = uu * 256 + t;
    *reinterpret_cast<uint4*>(kb2 + obase + u * 8) =
        *reinterpret_cast<const uint4*>(lds + u * 8);
  }
  __syncthreads();
  // ---- V ----
  #pragma unroll
  for (int i = 0; i < 4; ++i) {
    int idx = i * 256 + t, key = idx >> 4, F = (idx & 15) * 4;
    float4 f = *reinterpret_cast<const float4*>(vin + base + key * DH + F);
    int kgp = key >> 5, qd = (key >> 2) & 3, jj = ((key >> 4) & 1) * 4 + (key & 3);
    int u0 = kgp * 256 + (F >> 4) * 64 + qd * 16 + (F & 15);
    lds[(u0 + 0) * 8 + jj] = f2bf(f.x);
    lds[(u0 + 1) * 8 + jj] = f2bf(f.y);
    lds[(u0 + 2) * 8 + jj] = f2bf(f.z);
    lds[(u0 + 3) * 8 + jj] = f2bf(f.w);
  }
  __syncthreads();
  #pragma unroll
  for (int uu = 0; uu < 2; ++uu) {
    int u = uu * 256 + t;
    *reinterpret_cast<uint4*>(vt2 + obase + u * 8) =
        *reinterpret_cast<const uint4*>(lds + u * 8);
  }
}

// ---------------------------------------------------------------------------
// attn: grid (16,32), 256 threads (4 waves). Block owns q-tiles A=qa, B=31-qa.
// Flat step list (33 steps, pad to 34): s<nB -> (B, kv=s); else (A, kv=s-nB),
// nB=32-qa. Iteration i (17 total, identical for ALL blocks): slots s=2i,2i+1.
// Wave w: p=w>>1 handles slot 2i+p, rh=w&1 -> 32 q-rows. Staging role: wave w
// stages (w>>1 ? V : K) for slot (w&1): 8 contiguous stage16 (8KB stream).
// Double-buffered; prefetch kept in flight across raw s_barrier (vmcnt(8)).
// S^T = K.Q^T (16x16x32) -> phi in-register -> P^T B-frags -> O^T += V^T.P^T
// (16x16x16). Split-K parity merged once via LDS at the end.
// ---------------------------------------------------------------------------
__global__ __launch_bounds__(256, 2) void attn_kernel(
    const float* __restrict__ q,
    const unsigned short* __restrict__ kb2,
    const unsigned short* __restrict__ vt2,
    float* __restrict__ out)
{
  const int qa   = blockIdx.x;        // 0..15
  const int bh   = blockIdx.y;        // 0..31
  const int tid  = threadIdx.x;
  const int w    = tid >> 6;          // 0..3
  const int lane = tid & 63;
  const int low  = lane & 15;
  const int quad = lane >> 4;
  const int p    = w >> 1;            // step slot parity
  const int rh   = w & 1;             // q-row half
  const int nB   = 32 - qa;           // number of B-steps

  __shared__ __align__(16) unsigned short kls[2][2][4096];  // [buf][slot]
  __shared__ __align__(16) unsigned short vls[2][2][4096];

  const unsigned short* kb_h = kb2 + (size_t)bh * 32 * 4096;
  const unsigned short* v2_h = vt2 + (size_t)bh * 32 * 4096;

  // Q B-frags for both tiles (scaled bf16), registers for whole kernel
  short8 aqA[2][2], aqB[2][2];
  #pragma unroll
  for (int tsel = 0; tsel < 2; ++tsel) {
    const int qt = tsel ? (31 - qa) : qa;
    #pragma unroll
    for (int h = 0; h < 2; ++h) {
      const float* qp =
          q + ((size_t)bh * SEQ + qt * 64 + rh * 32 + h * 16 + low) * DH + quad * 8;
      #pragma unroll
      for (int ks = 0; ks < 2; ++ks) {
        float4 f0 = *reinterpret_cast<const float4*>(qp + ks * 32);
        float4 f1 = *reinterpret_cast<const float4*>(qp + ks * 32 + 4);
        uint4 uv;
        uv.x = packbf(f0.x * SCALE, f0.y * SCALE);
        uv.y = packbf(f0.z * SCALE, f0.w * SCALE);
        uv.z = packbf(f1.x * SCALE, f1.y * SCALE);
        uv.w = packbf(f1.z * SCALE, f1.w * SCALE);
        short8 a = __builtin_bit_cast(short8, uv);
        if (tsel) aqB[h][ks] = a; else aqA[h][ks] = a;
      }
    }
  }

  f32x4 oaccA[2][4], oaccB[2][4];
  #pragma unroll
  for (int h = 0; h < 2; ++h)
    #pragma unroll
    for (int i = 0; i < 4; ++i) {
      oaccA[h][i] = (f32x4){0.f, 0.f, 0.f, 0.f};
      oaccB[h][i] = (f32x4){0.f, 0.f, 0.f, 0.f};
    }

  // staging role
  const int slot = w & 1;
  const unsigned short* gsrc = (w >> 1) ? v2_h : kb_h;
  unsigned short* ldst0 = (w >> 1) ? &vls[0][slot][0] : &kls[0][slot][0];
  unsigned short* ldst1 = (w >> 1) ? &vls[1][slot][0] : &kls[1][slot][0];

  #define STAGE(I, B)                                                          \
    do {                                                                       \
      int s_ = 2 * (I) + slot; if (s_ > 32) s_ = 32;                           \
      const int T_ = (s_ < nB) ? s_ : (s_ - nB);                               \
      const unsigned short* gs_ = gsrc + (size_t)T_ * 4096;                    \
      unsigned short* ld_ = (B) ? ldst1 : ldst0;                               \
      _Pragma("unroll")                                                        \
      for (int r_ = 0; r_ < 8; ++r_)                                           \
        stage16(gs_ + (r_ * 64 + lane) * 8, ld_ + (r_ * 64 + lane) * 8);       \
    } while (0)

  #define COMPUTE(AQ, OACC)                                                    \
    do {                                                                       \
      _Pragma("unroll")                                                        \
      for (int ntp = 0; ntp < 2; ++ntp) {                                      \
        short8 vf[4];                                                          \
        _Pragma("unroll")                                                      \
        for (int ft = 0; ft < 4; ++ft)                                         \
          vf[ft] = *reinterpret_cast<const short8*>(                           \
              vT + ((ntp * 4 + ft) * 64 + quad * 16 + low) * 8);               \
        _Pragma("unroll")                                                      \
        for (int sub = 0; sub < 2; ++sub) {                                    \
          const int nt = ntp * 2 + sub;                                        \
          f32x4 s0 = (f32x4){0.f, 0.f, 0.f, 0.f};                              \
          f32x4 s1 = (f32x4){0.f, 0.f, 0.f, 0.f};                              \
          _Pragma("unroll")                                                    \
          for (int ks = 0; ks < 2; ++ks) {                                     \
            short8 kf = *reinterpret_cast<const short8*>(                      \
                kT + ((ks * 4 + quad) * 64 + nt * 16 + low) * 8);              \
            s0 = __builtin_amdgcn_mfma_f32_16x16x32_bf16(kf, AQ[0][ks], s0, 0, 0, 0); \
            s1 = __builtin_amdgcn_mfma_f32_16x16x32_bf16(kf, AQ[1][ks], s1, 0, 0, 0); \
          }                                                                    \
          _Pragma("unroll")                                                    \
          for (int h = 0; h < 2; ++h) {                                        \
            f32x4 sv = h ? s1 : s0;                                            \
            float pv[4];                                                       \
            _Pragma("unroll")                                                  \
            for (int r = 0; r < 4; ++r) {                                      \
              float x = sv[r];                                                 \
              pv[r] = __builtin_fmaf(0.5f * x, x, x);                          \
            }                                                                  \
            if (diag) {                                                        \
              _Pragma("unroll")                                                \
              for (int r = 0; r < 4; ++r)                                      \
                if ((nt * 16 + quad * 4 + r) > (rh * 32 + h * 16 + low))       \
                  pv[r] = 0.f;                                                 \
            }                                                                  \
            uint2 du; du.x = packbf(pv[0], pv[1]); du.y = packbf(pv[2], pv[3]);\
            short4b pf = __builtin_bit_cast(short4b, du);                      \
            _Pragma("unroll")                                                  \
            for (int ft = 0; ft < 4; ++ft) {                                   \
              short4b va = sub                                                 \
                  ? __builtin_shufflevector(vf[ft], vf[ft], 4, 5, 6, 7)        \
                  : __builtin_shufflevector(vf[ft], vf[ft], 0, 1, 2, 3);       \
              OACC[h][ft] = __builtin_amdgcn_mfma_f32_16x16x16bf16_1k(         \
                  va, pf, OACC[h][ft], 0, 0, 0);                               \
            }                                                                  \
          }                                                                    \
        }                                                                      \
      }                                                                        \
    } while (0)

  STAGE(0, 0);

  for (int i = 0; i < 17; ++i) {
    const int b = i & 1;
    __builtin_amdgcn_s_barrier();                       // buf b^1 free
    if (i < 16) {
      STAGE(i + 1, b ^ 1);                              // prefetch in flight
      asm volatile("s_waitcnt vmcnt(8)" ::: "memory");  // own slot-i loads landed
    } else {
      asm volatile("s_waitcnt vmcnt(0)" ::: "memory");
    }
    __builtin_amdgcn_s_barrier();                       // everyone's landed
    asm volatile("" ::: "memory");

    const int s = 2 * i + p;
    if (s > 32) continue;                               // only the single pad slot
    const bool diag = (s == nB - 1) || (s == 32);
    const unsigned short* kT = &kls[b][p][0];
    const unsigned short* vT = &vls[b][p][0];

    if (s >= nB) COMPUTE(aqA, oaccA);
    else         COMPUTE(aqB, oaccB);
  }

  // ---- split-K merge via LDS (reuse kls: 32KB) + epilogue ----
  __syncthreads();
  float* mb = reinterpret_cast<float*>(&kls[0][0][0]);
  float* mw = mb + rh * 4096;
  if (p == 1) {
    #pragma unroll
    for (int h = 0; h < 2; ++h)
      #pragma unroll
      for (int ft = 0; ft < 4; ++ft) {
        *reinterpret_cast<f32x4*>(mw + ((0 * 8 + h * 4 + ft) * 256 + lane * 4)) =
            oaccA[h][ft];
        *reinterpret_cast<f32x4*>(mw + ((1 * 8 + h * 4 + ft) * 256 + lane * 4)) =
            oaccB[h][ft];
      }
  }
  __syncthreads();
  if (p == 0) {
    #pragma unroll
    for (int tsel = 0; tsel < 2; ++tsel) {
      const int qt = tsel ? (31 - qa) : qa;
      #pragma unroll
      for (int h = 0; h < 2; ++h)
        #pragma unroll
        for (int ft = 0; ft < 4; ++ft) {
          f32x4 o = tsel ? oaccB[h][ft] : oaccA[h][ft];
          f32x4 m = *reinterpret_cast<const f32x4*>(
              mw + ((tsel * 8 + h * 4 + ft) * 256 + lane * 4));
          o += m;
          *reinterpret_cast<f32x4*>(
              out + ((size_t)bh * SEQ + qt * 64 + rh * 32 + h * 16 + low) * DH +
              ft * 16 + quad * 4) = o;
        }
    }
  }
}

extern "C" void kernel_launch(void* const* d_in, const int* in_sizes, int n_in,
                              void* d_out, int out_size, void* d_ws, size_t ws_size,
                              hipStream_t stream)
{
  const float* q = (const float*)d_in[0];
  const float* k = (const float*)d_in[1];
  const float* v = (const float*)d_in[2];
  float* out = (float*)d_out;

  unsigned short* kb2 = (unsigned short*)d_ws;             // 8.4 MB bf16 packed
  unsigned short* vt2 = kb2 + (size_t)BH_N * SEQ * DH;     // 8.4 MB bf16 packed

  prep_kernel<<<dim3(32, BH_N), 256, 0, stream>>>(k, v, kb2, vt2);
  attn_kernel<<<dim3(16, BH_N), 256, 0, stream>>>(q, kb2, vt2, out);
}